// Round 20
// baseline (3688.985 us; speedup 1.0000x reference)
//
#include <hip/hip_runtime.h>
#include <hip/hip_bf16.h>

#define SORB  64
#define HID   512
#define BATCH 4096
#define N3H   1536
#define KD    512
#define BK    64
#define PI_F  3.14159265358979f

typedef _Float16 half8 __attribute__((ext_vector_type(8)));
typedef float    floatx4 __attribute__((ext_vector_type(4)));

__device__ __forceinline__ void gload16(const void* g, void* l) {
    __builtin_amdgcn_global_load_lds(
        (const __attribute__((address_space(1))) void*)g,
        (__attribute__((address_space(3))) void*)l, 16, 0, 0);
}

__device__ __forceinline__ float sigmoidf_(float x) { return 1.f / (1.f + __expf(-x)); }
__device__ __forceinline__ float tanhf_(float x) {
    x = fminf(fmaxf(x, -15.f), 15.f);
    const float e2 = __expf(2.f * x);
    return (e2 - 1.f) / (e2 + 1.f);
}

__global__ __launch_bounds__(256) void convw_kernel(
    const float* __restrict__ w0, const float* __restrict__ w1, const float* __restrict__ w2,
    _Float16* __restrict__ o0, _Float16* __restrict__ o1, _Float16* __restrict__ o2)
{
    const int i = blockIdx.x * 256 + threadIdx.x;
    if (i < N3H * KD) {
        o0[i] = (_Float16)w0[i];
        o1[i] = (_Float16)w1[i];
        o2[i] = (_Float16)w2[i];
    }
}

__global__ __launch_bounds__(256) void init_kernel(
    float* __restrict__ amp, float* __restrict__ phase,
    int* __restrict__ nup, int* __restrict__ ndn)
{
    const int i = blockIdx.x * 256 + threadIdx.x;
    if (i < BATCH) { amp[i] = 1.f; phase[i] = 0.f; nup[i] = 0; ndn[i] = 0; }
}

// ================= step1: gh0 GEMM + fused gates0 (BM=32) =================
// Grid (8,128) = 1024 blocks, 256 thr = 4 waves; each wave owns one 16-wide
// j-slice (wid*16) across the full BM=32. acc[2][3] per thread.
__global__ __launch_bounds__(256) void step1_kernel(
    const _Float16* __restrict__ h0h_c, const _Float16* __restrict__ wh0,
    const float* __restrict__ Wih0, const int* __restrict__ bits,
    _Float16* __restrict__ h0h_n, int step)
{
    const int j0 = blockIdx.x * 64;
    const int m0 = blockIdx.y * 32;

    __shared__ __align__(16) _Float16 As[32 * BK];    // 4 KB
    __shared__ __align__(16) _Float16 Bs[192 * BK];   // 24 KB

    const int tid  = threadIdx.x;
    const int lane = tid & 63;
    const int wid  = tid >> 6;
    const int ku   = lane >> 4;

    floatx4 acc[2][3];
    const floatx4 z4 = {0.f, 0.f, 0.f, 0.f};
#pragma unroll
    for (int a = 0; a < 2; ++a)
#pragma unroll
        for (int g = 0; g < 3; ++g) acc[a][g] = z4;

    // A staging: 256 units (1/thread)
    const int pa = tid, rowa = pa >> 3, ca = (pa & 7) ^ (rowa & 7);
    const _Float16* a_src = h0h_c + (size_t)(m0 + rowa) * KD + ca * 8;
    _Float16* a_dst = As + (size_t)(wid * 64) * 8;
    // B staging: 1536 units (6/thread)
    const _Float16* b_srcp[6];
#pragma unroll
    for (int k2 = 0; k2 < 6; ++k2) {
        const int p = tid + k2 * 256, row = p >> 3, c = (p & 7) ^ (row & 7);
        const int grow = (row >> 6) * HID + j0 + (row & 63);
        b_srcp[k2] = wh0 + (size_t)grow * KD + c * 8;
    }
    _Float16* b_dst[6];
#pragma unroll
    for (int k2 = 0; k2 < 6; ++k2) b_dst[k2] = Bs + (size_t)(k2 * 256 + wid * 64) * 8;

    int aoff[2][2], boff[3][2];
#pragma unroll
    for (int mf = 0; mf < 2; ++mf) {
        const int r = mf * 16 + (lane & 15);
#pragma unroll
        for (int kk = 0; kk < 2; ++kk)
            aoff[mf][kk] = r * BK + (((kk * 4 + ku) ^ (r & 7)) * 8);
    }
#pragma unroll
    for (int g = 0; g < 3; ++g) {
        const int r = g * 64 + wid * 16 + (lane & 15);
#pragma unroll
        for (int kk = 0; kk < 2; ++kk)
            boff[g][kk] = r * BK + (((kk * 4 + ku) ^ (r & 7)) * 8);
    }

    for (int kt = 0; kt < 8; ++kt) {
        const int k0 = kt * BK;
        gload16(a_src + k0, a_dst);
#pragma unroll
        for (int k2 = 0; k2 < 6; ++k2) gload16(b_srcp[k2] + k0, b_dst[k2]);
        __syncthreads();
#pragma unroll
        for (int kk = 0; kk < 2; ++kk) {
            half8 af[2], bf[3];
#pragma unroll
            for (int mf = 0; mf < 2; ++mf) af[mf] = *(const half8*)(As + aoff[mf][kk]);
#pragma unroll
            for (int g = 0; g < 3; ++g) bf[g] = *(const half8*)(Bs + boff[g][kk]);
#pragma unroll
            for (int mf = 0; mf < 2; ++mf)
#pragma unroll
                for (int g = 0; g < 3; ++g)
                    acc[mf][g] = __builtin_amdgcn_mfma_f32_16x16x32_f16(
                        af[mf], bf[g], acc[mf][g], 0, 0, 0);
        }
        __syncthreads();
    }

    // fused gates0: h0n = (1-z)*n + z*h0
#pragma unroll
    for (int mf = 0; mf < 2; ++mf) {
        const floatx4 gr = acc[mf][0];
        const floatx4 gz = acc[mf][1];
        const floatx4 gn = acc[mf][2];
#pragma unroll
        for (int reg = 0; reg < 4; ++reg) {
            const int m = m0 + mf * 16 + (lane >> 4) * 4 + reg;
            const int j = j0 + wid * 16 + (lane & 15);
            float gir = 0.f, giz = 0.f, gin = 0.f;
            if (step > 0) {
                const int tb = bits[m * SORB + step - 1];
                gir = Wih0[j * 2 + tb];
                giz = Wih0[(HID + j) * 2 + tb];
                gin = Wih0[(2 * HID + j) * 2 + tb];
            }
            const float r  = sigmoidf_(gir + gr[reg]);
            const float zz = sigmoidf_(giz + gz[reg]);
            const float n  = tanhf_(gin + r * gn[reg]);
            const size_t idx = (size_t)m * HID + j;
            const float h  = (float)h0h_c[idx];
            h0h_n[idx] = (_Float16)((1.f - zz) * n + zz * h);
        }
    }
}

// ================= step2: dual-K GEMM (gi1 + gh1) + fused gates1 (BM=32) =================
__global__ __launch_bounds__(256) void step2_kernel(
    const _Float16* __restrict__ h0h_n, const _Float16* __restrict__ h1h_c,
    const _Float16* __restrict__ wi1,   const _Float16* __restrict__ wh1,
    _Float16* __restrict__ h1h_n)
{
    const int j0 = blockIdx.x * 64;
    const int m0 = blockIdx.y * 32;

    __shared__ __align__(16) _Float16 As[32 * BK];
    __shared__ __align__(16) _Float16 Bs[192 * BK];

    const int tid  = threadIdx.x;
    const int lane = tid & 63;
    const int wid  = tid >> 6;
    const int ku   = lane >> 4;

    floatx4 acc[2][3];
    floatx4 accn[2];
    const floatx4 z4 = {0.f, 0.f, 0.f, 0.f};
#pragma unroll
    for (int a = 0; a < 2; ++a) {
#pragma unroll
        for (int g = 0; g < 3; ++g) acc[a][g] = z4;
        accn[a] = z4;
    }

    _Float16* a_dst = As + (size_t)(wid * 64) * 8;
    _Float16* b_dst[6];
#pragma unroll
    for (int k2 = 0; k2 < 6; ++k2) b_dst[k2] = Bs + (size_t)(k2 * 256 + wid * 64) * 8;

    int aoff[2][2], boff[3][2];
#pragma unroll
    for (int mf = 0; mf < 2; ++mf) {
        const int r = mf * 16 + (lane & 15);
#pragma unroll
        for (int kk = 0; kk < 2; ++kk)
            aoff[mf][kk] = r * BK + (((kk * 4 + ku) ^ (r & 7)) * 8);
    }
#pragma unroll
    for (int g = 0; g < 3; ++g) {
        const int r = g * 64 + wid * 16 + (lane & 15);
#pragma unroll
        for (int kk = 0; kk < 2; ++kk)
            boff[g][kk] = r * BK + (((kk * 4 + ku) ^ (r & 7)) * 8);
    }

#pragma unroll 1
    for (int half = 0; half < 2; ++half) {
        const _Float16* Aop = half ? h1h_c : h0h_n;
        const _Float16* Wop = half ? wh1  : wi1;
        const int pa = tid, rowa = pa >> 3, ca = (pa & 7) ^ (rowa & 7);
        const _Float16* a_src = Aop + (size_t)(m0 + rowa) * KD + ca * 8;
        const _Float16* b_srcp[6];
#pragma unroll
        for (int k2 = 0; k2 < 6; ++k2) {
            const int p = tid + k2 * 256, row = p >> 3, c = (p & 7) ^ (row & 7);
            const int grow = (row >> 6) * HID + j0 + (row & 63);
            b_srcp[k2] = Wop + (size_t)grow * KD + c * 8;
        }

        for (int kt = 0; kt < 8; ++kt) {
            const int k0 = kt * BK;
            gload16(a_src + k0, a_dst);
#pragma unroll
            for (int k2 = 0; k2 < 6; ++k2) gload16(b_srcp[k2] + k0, b_dst[k2]);
            __syncthreads();
#pragma unroll
            for (int kk = 0; kk < 2; ++kk) {
                half8 af[2], bf[3];
#pragma unroll
                for (int mf = 0; mf < 2; ++mf) af[mf] = *(const half8*)(As + aoff[mf][kk]);
#pragma unroll
                for (int g = 0; g < 3; ++g) bf[g] = *(const half8*)(Bs + boff[g][kk]);
#pragma unroll
                for (int mf = 0; mf < 2; ++mf) {
                    acc[mf][0] = __builtin_amdgcn_mfma_f32_16x16x32_f16(
                        af[mf], bf[0], acc[mf][0], 0, 0, 0);
                    acc[mf][1] = __builtin_amdgcn_mfma_f32_16x16x32_f16(
                        af[mf], bf[1], acc[mf][1], 0, 0, 0);
                    if (half == 0)
                        acc[mf][2] = __builtin_amdgcn_mfma_f32_16x16x32_f16(
                            af[mf], bf[2], acc[mf][2], 0, 0, 0);
                    else
                        accn[mf] = __builtin_amdgcn_mfma_f32_16x16x32_f16(
                            af[mf], bf[2], accn[mf], 0, 0, 0);
                }
            }
            __syncthreads();
        }
    }

    // fused gates1: r=sig(gi_r+gh_r), z=sig(gi_z+gh_z), n=tanh(gi_n + r*gh_n)
#pragma unroll
    for (int mf = 0; mf < 2; ++mf) {
        const floatx4 grz = acc[mf][0];
        const floatx4 gzz = acc[mf][1];
        const floatx4 gin = acc[mf][2];
        const floatx4 ghn = accn[mf];
#pragma unroll
        for (int reg = 0; reg < 4; ++reg) {
            const int m = m0 + mf * 16 + (lane >> 4) * 4 + reg;
            const int j = j0 + wid * 16 + (lane & 15);
            const float r  = sigmoidf_(grz[reg]);
            const float zz = sigmoidf_(gzz[reg]);
            const float n  = tanhf_(gin[reg] + r * ghn[reg]);
            const size_t idx = (size_t)m * HID + j;
            const float h  = (float)h1h_c[idx];
            h1h_n[idx] = (_Float16)((1.f - zz) * n + zz * h);
        }
    }
}

// ================= head =================
__global__ __launch_bounds__(256) void head_kernel(
    const _Float16* __restrict__ h1h_n,
    const float* __restrict__ Wamp, const float* __restrict__ bamp,
    const float* __restrict__ Wph,  const float* __restrict__ bph,
    const int* __restrict__ bits,
    float* __restrict__ amp, float* __restrict__ phase,
    int* __restrict__ nup, int* __restrict__ ndn,
    float* __restrict__ out, int step)
{
    const int lane = threadIdx.x & 63;
    const int m    = blockIdx.x * 4 + (threadIdx.x >> 6);
    const half8 hv = *(const half8*)(h1h_n + (size_t)m * HID + lane * 8);
    float d0 = 0.f, d1 = 0.f, d2 = 0.f, d3 = 0.f;
#pragma unroll
    for (int e = 0; e < 8; ++e) {
        const int j = lane * 8 + e;
        const float hn = (float)hv[e];
        d0 += hn * Wamp[j];       d1 += hn * Wamp[HID + j];
        d2 += hn * Wph[j];        d3 += hn * Wph[HID + j];
    }
#pragma unroll
    for (int off = 1; off < 64; off <<= 1) {
        d0 += __shfl_xor(d0, off); d1 += __shfl_xor(d1, off);
        d2 += __shfl_xor(d2, off); d3 += __shfl_xor(d3, off);
    }
    if (lane == 0) {
        const float a0 = d0 + bamp[0];
        const float a1 = d1 + bamp[1];
        const float mx = fmaxf(a0, a1);
        const float e0 = __expf(a0 - mx), e1 = __expf(a1 - mx);
        const float inv = 1.f / (e0 + e1);
        float ya0 = sqrtf(e0 * inv), ya1 = sqrtf(e1 * inv);
        const float p0 = d2 + bph[0];
        const float p1 = d3 + bph[1];
        const float yp0 = PI_F * p0 / (1.f + fabsf(p0));
        const float yp1 = PI_F * p1 / (1.f + fabsf(p1));
        const int even = ((step & 1) == 0);
        const int cnt = even ? nup[m] : ndn[m];
        if (step >= 32) {  // MIN_I
            const int lower = (step >> 1) - 16;
            const float m0v = (cnt > lower) ? ya0 : 0.f;
            const float m1v = (cnt < 16) ? ya1 : 0.f;
            const float nrm = sqrtf(m0v * m0v + m1v * m1v + 1e-12f);
            ya0 = m0v / nrm; ya1 = m1v / nrm;
        }
        const int bi = bits[m * SORB + step];
        const float na = amp[m] * (bi ? ya1 : ya0);
        const float np = phase[m] + (bi ? yp1 : yp0);
        amp[m] = na; phase[m] = np;
        if (bi) { if (even) nup[m] = cnt + 1; else ndn[m] = cnt + 1; }
        if (step == SORB - 1) {
            out[m * 2 + 0] = na;
            out[m * 2 + 1] = np;
        }
    }
}

extern "C" void kernel_launch(void* const* d_in, const int* in_sizes, int n_in,
                              void* d_out, int out_size, void* d_ws, size_t ws_size,
                              hipStream_t stream) {
    const int*   bits = (const int*)d_in[0];
    const float* Wih0 = (const float*)d_in[1];
    const float* Whh0 = (const float*)d_in[2];
    const float* Wih1 = (const float*)d_in[3];
    const float* Whh1 = (const float*)d_in[4];
    const float* Wamp = (const float*)d_in[5];
    const float* bamp = (const float*)d_in[6];
    const float* Wph  = (const float*)d_in[7];
    const float* bph  = (const float*)d_in[8];
    float* out = (float*)d_out;

    char* ws = (char*)d_ws;
    size_t off = 0;
    auto alloc = [&](size_t bytes) {
        void* p = ws + off;
        off = (off + bytes + 255) & ~(size_t)255;
        return p;
    };
    _Float16* wh0 = (_Float16*)alloc((size_t)N3H * KD * 2);
    _Float16* wi1 = (_Float16*)alloc((size_t)N3H * KD * 2);
    _Float16* wh1 = (_Float16*)alloc((size_t)N3H * KD * 2);
    _Float16* h0hA = (_Float16*)alloc((size_t)BATCH * HID * 2);
    _Float16* h0hB = (_Float16*)alloc((size_t)BATCH * HID * 2);
    _Float16* h1hA = (_Float16*)alloc((size_t)BATCH * HID * 2);
    _Float16* h1hB = (_Float16*)alloc((size_t)BATCH * HID * 2);
    float*    amp   = (float*)alloc((size_t)BATCH * 4);
    float*    phase = (float*)alloc((size_t)BATCH * 4);
    int*      nup   = (int*)alloc((size_t)BATCH * 4);
    int*      ndn   = (int*)alloc((size_t)BATCH * 4);

    _Float16* h0h[2] = {h0hA, h0hB};
    _Float16* h1h[2] = {h1hA, h1hB};

    hipMemsetAsync(h0hA, 0, (size_t)BATCH * HID * 2, stream);
    hipMemsetAsync(h1hA, 0, (size_t)BATCH * HID * 2, stream);
    convw_kernel<<<(N3H * KD + 255) / 256, 256, 0, stream>>>(Whh0, Wih1, Whh1, wh0, wi1, wh1);
    init_kernel<<<BATCH / 256, 256, 0, stream>>>(amp, phase, nup, ndn);

    for (int s = 0; s < SORB; ++s) {
        const int cur = s & 1, nxt = cur ^ 1;
        step1_kernel<<<dim3(8, 128), 256, 0, stream>>>(
            h0h[cur], wh0, Wih0, bits, h0h[nxt], s);
        step2_kernel<<<dim3(8, 128), 256, 0, stream>>>(
            h0h[nxt], h1h[cur], wi1, wh1, h1h[nxt]);
        head_kernel<<<BATCH / 4, 256, 0, stream>>>(
            h1h[nxt], Wamp, bamp, Wph, bph, bits, amp, phase, nup, ndn, out, s);
    }
}

// Round 21
// 3061.501 us; speedup vs baseline: 1.2050x; 1.2050x over previous
//
#include <hip/hip_runtime.h>
#include <hip/hip_bf16.h>

#define SORB  64
#define HID   512
#define BATCH 4096
#define N3H   1536
#define KD    512
#define BK    64
#define PI_F  3.14159265358979f

typedef _Float16 half8 __attribute__((ext_vector_type(8)));
typedef float    floatx4 __attribute__((ext_vector_type(4)));

__device__ __forceinline__ void gload16(const void* g, void* l) {
    __builtin_amdgcn_global_load_lds(
        (const __attribute__((address_space(1))) void*)g,
        (__attribute__((address_space(3))) void*)l, 16, 0, 0);
}

__device__ __forceinline__ float sigmoidf_(float x) { return 1.f / (1.f + __expf(-x)); }
__device__ __forceinline__ float tanhf_(float x) {
    x = fminf(fmaxf(x, -15.f), 15.f);
    const float e2 = __expf(2.f * x);
    return (e2 - 1.f) / (e2 + 1.f);
}

__global__ __launch_bounds__(256) void convw_kernel(
    const float* __restrict__ w0, const float* __restrict__ w1, const float* __restrict__ w2,
    _Float16* __restrict__ o0, _Float16* __restrict__ o1, _Float16* __restrict__ o2)
{
    const int i = blockIdx.x * 256 + threadIdx.x;
    if (i < N3H * KD) {
        o0[i] = (_Float16)w0[i];
        o1[i] = (_Float16)w1[i];
        o2[i] = (_Float16)w2[i];
    }
}

__global__ __launch_bounds__(256) void init_kernel(
    float* __restrict__ amp, float* __restrict__ phase,
    int* __restrict__ nup, int* __restrict__ ndn)
{
    const int i = blockIdx.x * 256 + threadIdx.x;
    if (i < BATCH) { amp[i] = 1.f; phase[i] = 0.f; nup[i] = 0; ndn[i] = 0; }
}

// ================= step1: gh0 GEMM + fused gates0 (f16 h-state only) =================
// Grid (8,64), 256 thr = 4 waves (2m x 2j). BM=64, J=64 (B 192 rows), BK=64.
// Verified single-buffer K-loop: global_load_lds(16B) + XOR-swizzled global source.
// Note: linear block id = x + 8y, so bid%8 = j-slice -> each XCD's L2 holds one
// 196 KB B-panel (accidentally XCD-optimal).
__global__ __launch_bounds__(256) void step1_kernel(
    const _Float16* __restrict__ h0h_c, const _Float16* __restrict__ wh0,
    const float* __restrict__ Wih0, const int* __restrict__ bits,
    _Float16* __restrict__ h0h_n, int step)
{
    const int j0 = blockIdx.x * 64;
    const int m0 = blockIdx.y * 64;

    __shared__ __align__(16) _Float16 As[64 * BK];    // 8 KB
    __shared__ __align__(16) _Float16 Bs[192 * BK];   // 24 KB

    const int tid  = threadIdx.x;
    const int lane = tid & 63;
    const int wid  = tid >> 6;
    const int wm   = wid >> 1, wj = wid & 1;
    const int ku   = lane >> 4;

    floatx4 acc[2][2][3];
    const floatx4 z4 = {0.f, 0.f, 0.f, 0.f};
#pragma unroll
    for (int a = 0; a < 2; ++a)
#pragma unroll
        for (int b = 0; b < 2; ++b)
#pragma unroll
            for (int g = 0; g < 3; ++g) acc[a][b][g] = z4;

    const _Float16* a_srcp[2];
#pragma unroll
    for (int k2 = 0; k2 < 2; ++k2) {
        const int p = tid + k2 * 256, row = p >> 3, c = (p & 7) ^ (row & 7);
        a_srcp[k2] = h0h_c + (size_t)(m0 + row) * KD + c * 8;
    }
    const _Float16* b_srcp[6];
#pragma unroll
    for (int k2 = 0; k2 < 6; ++k2) {
        const int p = tid + k2 * 256, row = p >> 3, c = (p & 7) ^ (row & 7);
        const int grow = (row >> 6) * HID + j0 + (row & 63);
        b_srcp[k2] = wh0 + (size_t)grow * KD + c * 8;
    }
    _Float16* a_dst[2];
#pragma unroll
    for (int k2 = 0; k2 < 2; ++k2) a_dst[k2] = As + (size_t)(k2 * 256 + wid * 64) * 8;
    _Float16* b_dst[6];
#pragma unroll
    for (int k2 = 0; k2 < 6; ++k2) b_dst[k2] = Bs + (size_t)(k2 * 256 + wid * 64) * 8;

    int aoff[2][2], boff[2][3][2];
#pragma unroll
    for (int mf = 0; mf < 2; ++mf) {
        const int r = wm * 32 + mf * 16 + (lane & 15);
#pragma unroll
        for (int kk = 0; kk < 2; ++kk)
            aoff[mf][kk] = r * BK + (((kk * 4 + ku) ^ (r & 7)) * 8);
    }
#pragma unroll
    for (int jf = 0; jf < 2; ++jf)
#pragma unroll
        for (int g = 0; g < 3; ++g) {
            const int r = g * 64 + wj * 32 + jf * 16 + (lane & 15);
#pragma unroll
            for (int kk = 0; kk < 2; ++kk)
                boff[jf][g][kk] = r * BK + (((kk * 4 + ku) ^ (r & 7)) * 8);
        }

    for (int kt = 0; kt < 8; ++kt) {
        const int k0 = kt * BK;
#pragma unroll
        for (int k2 = 0; k2 < 2; ++k2) gload16(a_srcp[k2] + k0, a_dst[k2]);
#pragma unroll
        for (int k2 = 0; k2 < 6; ++k2) gload16(b_srcp[k2] + k0, b_dst[k2]);
        __syncthreads();
#pragma unroll
        for (int kk = 0; kk < 2; ++kk) {
            half8 af[2], bf[2][3];
#pragma unroll
            for (int mf = 0; mf < 2; ++mf) af[mf] = *(const half8*)(As + aoff[mf][kk]);
#pragma unroll
            for (int jf = 0; jf < 2; ++jf)
#pragma unroll
                for (int g = 0; g < 3; ++g) bf[jf][g] = *(const half8*)(Bs + boff[jf][g][kk]);
#pragma unroll
            for (int mf = 0; mf < 2; ++mf)
#pragma unroll
                for (int jf = 0; jf < 2; ++jf)
#pragma unroll
                    for (int g = 0; g < 3; ++g)
                        acc[mf][jf][g] = __builtin_amdgcn_mfma_f32_16x16x32_f16(
                            af[mf], bf[jf][g], acc[mf][jf][g], 0, 0, 0);
        }
        __syncthreads();
    }

    // fused gates0: h0n = (1-z)*n + z*h0   (h-state f16-only)
#pragma unroll
    for (int mf = 0; mf < 2; ++mf)
#pragma unroll
        for (int jf = 0; jf < 2; ++jf) {
            const floatx4 gr = acc[mf][jf][0];
            const floatx4 gz = acc[mf][jf][1];
            const floatx4 gn = acc[mf][jf][2];
#pragma unroll
            for (int reg = 0; reg < 4; ++reg) {
                const int m = m0 + wm * 32 + mf * 16 + (lane >> 4) * 4 + reg;
                const int j = j0 + wj * 32 + jf * 16 + (lane & 15);
                float gir = 0.f, giz = 0.f, gin = 0.f;
                if (step > 0) {
                    const int tb = bits[m * SORB + step - 1];
                    gir = Wih0[j * 2 + tb];
                    giz = Wih0[(HID + j) * 2 + tb];
                    gin = Wih0[(2 * HID + j) * 2 + tb];
                }
                const float r  = sigmoidf_(gir + gr[reg]);
                const float zz = sigmoidf_(giz + gz[reg]);
                const float n  = tanhf_(gin + r * gn[reg]);
                const size_t idx = (size_t)m * HID + j;
                const float h  = (float)h0h_c[idx];
                h0h_n[idx] = (_Float16)((1.f - zz) * n + zz * h);
            }
        }
}

// ================= step2: dual-K GEMM (gi1 + gh1) + fused gates1 =================
// acc = h0n @ wi1^T + h1c @ wh1^T; n-gate gh kept in separate accumulator accn
// (GRU needs n = tanh(gi_n + r*gh_n), not tanh(gi_n + gh_n)).
__global__ __launch_bounds__(256) void step2_kernel(
    const _Float16* __restrict__ h0h_n, const _Float16* __restrict__ h1h_c,
    const _Float16* __restrict__ wi1,   const _Float16* __restrict__ wh1,
    _Float16* __restrict__ h1h_n)
{
    const int j0 = blockIdx.x * 64;
    const int m0 = blockIdx.y * 64;

    __shared__ __align__(16) _Float16 As[64 * BK];
    __shared__ __align__(16) _Float16 Bs[192 * BK];

    const int tid  = threadIdx.x;
    const int lane = tid & 63;
    const int wid  = tid >> 6;
    const int wm   = wid >> 1, wj = wid & 1;
    const int ku   = lane >> 4;

    floatx4 acc[2][2][3];
    floatx4 accn[2][2];
    const floatx4 z4 = {0.f, 0.f, 0.f, 0.f};
#pragma unroll
    for (int a = 0; a < 2; ++a)
#pragma unroll
        for (int b = 0; b < 2; ++b) {
#pragma unroll
            for (int g = 0; g < 3; ++g) acc[a][b][g] = z4;
            accn[a][b] = z4;
        }

    _Float16* a_dst[2];
#pragma unroll
    for (int k2 = 0; k2 < 2; ++k2) a_dst[k2] = As + (size_t)(k2 * 256 + wid * 64) * 8;
    _Float16* b_dst[6];
#pragma unroll
    for (int k2 = 0; k2 < 6; ++k2) b_dst[k2] = Bs + (size_t)(k2 * 256 + wid * 64) * 8;

    int aoff[2][2], boff[2][3][2];
#pragma unroll
    for (int mf = 0; mf < 2; ++mf) {
        const int r = wm * 32 + mf * 16 + (lane & 15);
#pragma unroll
        for (int kk = 0; kk < 2; ++kk)
            aoff[mf][kk] = r * BK + (((kk * 4 + ku) ^ (r & 7)) * 8);
    }
#pragma unroll
    for (int jf = 0; jf < 2; ++jf)
#pragma unroll
        for (int g = 0; g < 3; ++g) {
            const int r = g * 64 + wj * 32 + jf * 16 + (lane & 15);
#pragma unroll
            for (int kk = 0; kk < 2; ++kk)
                boff[jf][g][kk] = r * BK + (((kk * 4 + ku) ^ (r & 7)) * 8);
        }

#pragma unroll 1
    for (int half = 0; half < 2; ++half) {
        const _Float16* Aop = half ? h1h_c : h0h_n;
        const _Float16* Wop = half ? wh1  : wi1;
        const _Float16* a_srcp[2];
#pragma unroll
        for (int k2 = 0; k2 < 2; ++k2) {
            const int p = tid + k2 * 256, row = p >> 3, c = (p & 7) ^ (row & 7);
            a_srcp[k2] = Aop + (size_t)(m0 + row) * KD + c * 8;
        }
        const _Float16* b_srcp[6];
#pragma unroll
        for (int k2 = 0; k2 < 6; ++k2) {
            const int p = tid + k2 * 256, row = p >> 3, c = (p & 7) ^ (row & 7);
            const int grow = (row >> 6) * HID + j0 + (row & 63);
            b_srcp[k2] = Wop + (size_t)grow * KD + c * 8;
        }

        for (int kt = 0; kt < 8; ++kt) {
            const int k0 = kt * BK;
#pragma unroll
            for (int k2 = 0; k2 < 2; ++k2) gload16(a_srcp[k2] + k0, a_dst[k2]);
#pragma unroll
            for (int k2 = 0; k2 < 6; ++k2) gload16(b_srcp[k2] + k0, b_dst[k2]);
            __syncthreads();
#pragma unroll
            for (int kk = 0; kk < 2; ++kk) {
                half8 af[2], bf[2][3];
#pragma unroll
                for (int mf = 0; mf < 2; ++mf) af[mf] = *(const half8*)(As + aoff[mf][kk]);
#pragma unroll
                for (int jf = 0; jf < 2; ++jf)
#pragma unroll
                    for (int g = 0; g < 3; ++g) bf[jf][g] = *(const half8*)(Bs + boff[jf][g][kk]);
#pragma unroll
                for (int mf = 0; mf < 2; ++mf)
#pragma unroll
                    for (int jf = 0; jf < 2; ++jf) {
                        acc[mf][jf][0] = __builtin_amdgcn_mfma_f32_16x16x32_f16(
                            af[mf], bf[jf][0], acc[mf][jf][0], 0, 0, 0);
                        acc[mf][jf][1] = __builtin_amdgcn_mfma_f32_16x16x32_f16(
                            af[mf], bf[jf][1], acc[mf][jf][1], 0, 0, 0);
                        if (half == 0)
                            acc[mf][jf][2] = __builtin_amdgcn_mfma_f32_16x16x32_f16(
                                af[mf], bf[jf][2], acc[mf][jf][2], 0, 0, 0);
                        else
                            accn[mf][jf] = __builtin_amdgcn_mfma_f32_16x16x32_f16(
                                af[mf], bf[jf][2], accn[mf][jf], 0, 0, 0);
                    }
            }
            __syncthreads();
        }
    }

    // fused gates1: r=sig(gi_r+gh_r), z=sig(gi_z+gh_z), n=tanh(gi_n + r*gh_n)
#pragma unroll
    for (int mf = 0; mf < 2; ++mf)
#pragma unroll
        for (int jf = 0; jf < 2; ++jf) {
            const floatx4 grz = acc[mf][jf][0];
            const floatx4 gzz = acc[mf][jf][1];
            const floatx4 gin = acc[mf][jf][2];
            const floatx4 ghn = accn[mf][jf];
#pragma unroll
            for (int reg = 0; reg < 4; ++reg) {
                const int m = m0 + wm * 32 + mf * 16 + (lane >> 4) * 4 + reg;
                const int j = j0 + wj * 32 + jf * 16 + (lane & 15);
                const float r  = sigmoidf_(grz[reg]);
                const float zz = sigmoidf_(gzz[reg]);
                const float n  = tanhf_(gin[reg] + r * ghn[reg]);
                const size_t idx = (size_t)m * HID + j;
                const float h  = (float)h1h_c[idx];
                h1h_n[idx] = (_Float16)((1.f - zz) * n + zz * h);
            }
        }
}

// ================= head =================
__global__ __launch_bounds__(256) void head_kernel(
    const _Float16* __restrict__ h1h_n,
    const float* __restrict__ Wamp, const float* __restrict__ bamp,
    const float* __restrict__ Wph,  const float* __restrict__ bph,
    const int* __restrict__ bits,
    float* __restrict__ amp, float* __restrict__ phase,
    int* __restrict__ nup, int* __restrict__ ndn,
    float* __restrict__ out, int step)
{
    const int lane = threadIdx.x & 63;
    const int m    = blockIdx.x * 4 + (threadIdx.x >> 6);
    const half8 hv = *(const half8*)(h1h_n + (size_t)m * HID + lane * 8);
    float d0 = 0.f, d1 = 0.f, d2 = 0.f, d3 = 0.f;
#pragma unroll
    for (int e = 0; e < 8; ++e) {
        const int j = lane * 8 + e;
        const float hn = (float)hv[e];
        d0 += hn * Wamp[j];       d1 += hn * Wamp[HID + j];
        d2 += hn * Wph[j];        d3 += hn * Wph[HID + j];
    }
#pragma unroll
    for (int off = 1; off < 64; off <<= 1) {
        d0 += __shfl_xor(d0, off); d1 += __shfl_xor(d1, off);
        d2 += __shfl_xor(d2, off); d3 += __shfl_xor(d3, off);
    }
    if (lane == 0) {
        const float a0 = d0 + bamp[0];
        const float a1 = d1 + bamp[1];
        const float mx = fmaxf(a0, a1);
        const float e0 = __expf(a0 - mx), e1 = __expf(a1 - mx);
        const float inv = 1.f / (e0 + e1);
        float ya0 = sqrtf(e0 * inv), ya1 = sqrtf(e1 * inv);
        const float p0 = d2 + bph[0];
        const float p1 = d3 + bph[1];
        const float yp0 = PI_F * p0 / (1.f + fabsf(p0));
        const float yp1 = PI_F * p1 / (1.f + fabsf(p1));
        const int even = ((step & 1) == 0);
        const int cnt = even ? nup[m] : ndn[m];
        if (step >= 32) {  // MIN_I
            const int lower = (step >> 1) - 16;
            const float m0v = (cnt > lower) ? ya0 : 0.f;
            const float m1v = (cnt < 16) ? ya1 : 0.f;
            const float nrm = sqrtf(m0v * m0v + m1v * m1v + 1e-12f);
            ya0 = m0v / nrm; ya1 = m1v / nrm;
        }
        const int bi = bits[m * SORB + step];
        const float na = amp[m] * (bi ? ya1 : ya0);
        const float np = phase[m] + (bi ? yp1 : yp0);
        amp[m] = na; phase[m] = np;
        if (bi) { if (even) nup[m] = cnt + 1; else ndn[m] = cnt + 1; }
        if (step == SORB - 1) {
            out[m * 2 + 0] = na;
            out[m * 2 + 1] = np;
        }
    }
}

extern "C" void kernel_launch(void* const* d_in, const int* in_sizes, int n_in,
                              void* d_out, int out_size, void* d_ws, size_t ws_size,
                              hipStream_t stream) {
    const int*   bits = (const int*)d_in[0];
    const float* Wih0 = (const float*)d_in[1];
    const float* Whh0 = (const float*)d_in[2];
    const float* Wih1 = (const float*)d_in[3];
    const float* Whh1 = (const float*)d_in[4];
    const float* Wamp = (const float*)d_in[5];
    const float* bamp = (const float*)d_in[6];
    const float* Wph  = (const float*)d_in[7];
    const float* bph  = (const float*)d_in[8];
    float* out = (float*)d_out;

    char* ws = (char*)d_ws;
    size_t off = 0;
    auto alloc = [&](size_t bytes) {
        void* p = ws + off;
        off = (off + bytes + 255) & ~(size_t)255;
        return p;
    };
    _Float16* wh0 = (_Float16*)alloc((size_t)N3H * KD * 2);
    _Float16* wi1 = (_Float16*)alloc((size_t)N3H * KD * 2);
    _Float16* wh1 = (_Float16*)alloc((size_t)N3H * KD * 2);
    _Float16* h0hA = (_Float16*)alloc((size_t)BATCH * HID * 2);
    _Float16* h0hB = (_Float16*)alloc((size_t)BATCH * HID * 2);
    _Float16* h1hA = (_Float16*)alloc((size_t)BATCH * HID * 2);
    _Float16* h1hB = (_Float16*)alloc((size_t)BATCH * HID * 2);
    float*    amp   = (float*)alloc((size_t)BATCH * 4);
    float*    phase = (float*)alloc((size_t)BATCH * 4);
    int*      nup   = (int*)alloc((size_t)BATCH * 4);
    int*      ndn   = (int*)alloc((size_t)BATCH * 4);

    _Float16* h0h[2] = {h0hA, h0hB};
    _Float16* h1h[2] = {h1hA, h1hB};

    hipMemsetAsync(h0hA, 0, (size_t)BATCH * HID * 2, stream);
    hipMemsetAsync(h1hA, 0, (size_t)BATCH * HID * 2, stream);
    convw_kernel<<<(N3H * KD + 255) / 256, 256, 0, stream>>>(Whh0, Wih1, Whh1, wh0, wi1, wh1);
    init_kernel<<<BATCH / 256, 256, 0, stream>>>(amp, phase, nup, ndn);

    for (int s = 0; s < SORB; ++s) {
        const int cur = s & 1, nxt = cur ^ 1;
        step1_kernel<<<dim3(8, 64), 256, 0, stream>>>(
            h0h[cur], wh0, Wih0, bits, h0h[nxt], s);
        step2_kernel<<<dim3(8, 64), 256, 0, stream>>>(
            h0h[nxt], h1h[cur], wi1, wh1, h1h[nxt]);
        head_kernel<<<BATCH / 4, 256, 0, stream>>>(
            h1h[nxt], Wamp, bamp, Wph, bph, bits, amp, phase, nup, ndn, out, s);
    }
}

// Round 22
// 2826.611 us; speedup vs baseline: 1.3051x; 1.0831x over previous
//
#include <hip/hip_runtime.h>
#include <hip/hip_bf16.h>

#define SORB  64
#define HID   512
#define BATCH 4096
#define N3H   1536
#define KD    512
#define BK    64
#define PI_F  3.14159265358979f

typedef _Float16 half8 __attribute__((ext_vector_type(8)));
typedef float    floatx4 __attribute__((ext_vector_type(4)));

__device__ __forceinline__ void gload16(const void* g, void* l) {
    __builtin_amdgcn_global_load_lds(
        (const __attribute__((address_space(1))) void*)g,
        (__attribute__((address_space(3))) void*)l, 16, 0, 0);
}

__device__ __forceinline__ float sigmoidf_(float x) { return 1.f / (1.f + __expf(-x)); }
__device__ __forceinline__ float tanhf_(float x) {
    x = fminf(fmaxf(x, -15.f), 15.f);
    const float e2 = __expf(2.f * x);
    return (e2 - 1.f) / (e2 + 1.f);
}

__global__ __launch_bounds__(256) void convw_kernel(
    const float* __restrict__ w0, const float* __restrict__ w1, const float* __restrict__ w2,
    _Float16* __restrict__ o0, _Float16* __restrict__ o1, _Float16* __restrict__ o2)
{
    const int i = blockIdx.x * 256 + threadIdx.x;
    if (i < N3H * KD) {
        o0[i] = (_Float16)w0[i];
        o1[i] = (_Float16)w1[i];
        o2[i] = (_Float16)w2[i];
    }
}

__global__ __launch_bounds__(256) void init_kernel(
    float* __restrict__ amp, float* __restrict__ phase,
    int* __restrict__ nup, int* __restrict__ ndn)
{
    const int i = blockIdx.x * 256 + threadIdx.x;
    if (i < BATCH) { amp[i] = 1.f; phase[i] = 0.f; nup[i] = 0; ndn[i] = 0; }
}

// ---------------- head row (R16-verified) ----------------
__device__ __forceinline__ void head_row(
    const _Float16* __restrict__ h1, int m,
    const float* __restrict__ Wamp, const float* __restrict__ bamp,
    const float* __restrict__ Wph,  const float* __restrict__ bph,
    const int* __restrict__ bits,
    float* __restrict__ amp, float* __restrict__ phase,
    int* __restrict__ nup, int* __restrict__ ndn,
    float* __restrict__ out, int step, int lane)
{
    const half8 hv = *(const half8*)(h1 + (size_t)m * HID + lane * 8);
    float d0 = 0.f, d1 = 0.f, d2 = 0.f, d3 = 0.f;
#pragma unroll
    for (int e = 0; e < 8; ++e) {
        const int j = lane * 8 + e;
        const float hn = (float)hv[e];
        d0 += hn * Wamp[j];       d1 += hn * Wamp[HID + j];
        d2 += hn * Wph[j];        d3 += hn * Wph[HID + j];
    }
#pragma unroll
    for (int off = 1; off < 64; off <<= 1) {
        d0 += __shfl_xor(d0, off); d1 += __shfl_xor(d1, off);
        d2 += __shfl_xor(d2, off); d3 += __shfl_xor(d3, off);
    }
    if (lane == 0) {
        const float a0 = d0 + bamp[0];
        const float a1 = d1 + bamp[1];
        const float mx = fmaxf(a0, a1);
        const float e0 = __expf(a0 - mx), e1 = __expf(a1 - mx);
        const float inv = 1.f / (e0 + e1);
        float ya0 = sqrtf(e0 * inv), ya1 = sqrtf(e1 * inv);
        const float p0 = d2 + bph[0];
        const float p1 = d3 + bph[1];
        const float yp0 = PI_F * p0 / (1.f + fabsf(p0));
        const float yp1 = PI_F * p1 / (1.f + fabsf(p1));
        const int even = ((step & 1) == 0);
        const int cnt = even ? nup[m] : ndn[m];
        if (step >= 32) {  // MIN_I
            const int lower = (step >> 1) - 16;
            const float m0v = (cnt > lower) ? ya0 : 0.f;
            const float m1v = (cnt < 16) ? ya1 : 0.f;
            const float nrm = sqrtf(m0v * m0v + m1v * m1v + 1e-12f);
            ya0 = m0v / nrm; ya1 = m1v / nrm;
        }
        const int bi = bits[m * SORB + step];
        const float na = amp[m] * (bi ? ya1 : ya0);
        const float np = phase[m] + (bi ? yp1 : yp0);
        amp[m] = na; phase[m] = np;
        if (bi) { if (even) nup[m] = cnt + 1; else ndn[m] = cnt + 1; }
        if (step == SORB - 1) {
            out[m * 2 + 0] = na;
            out[m * 2 + 1] = np;
        }
    }
}

// ====== step1(s) [blocks 0..511] || head(s-1) [blocks 512..639] ======
// head(s-1) reads h1h_p (written by step2(s-1), earlier in-stream) and per-row
// scalars; step1 reads h0h_c/wh0/Wih0/bits, writes h0h_n. Disjoint -> no hazard,
// and the 128 tiny head blocks finish well before the GEMM blocks (no critical-
// path cost; deletes the separate head launch + its drain gap).
__global__ __launch_bounds__(256) void step1_kernel(
    const _Float16* __restrict__ h0h_c, const _Float16* __restrict__ wh0,
    const float* __restrict__ Wih0, const int* __restrict__ bits,
    _Float16* __restrict__ h0h_n, int step,
    const _Float16* __restrict__ h1h_p,
    const float* __restrict__ Wamp, const float* __restrict__ bamp,
    const float* __restrict__ Wph,  const float* __restrict__ bph,
    float* __restrict__ amp, float* __restrict__ phase,
    int* __restrict__ nup, int* __restrict__ ndn, float* __restrict__ out)
{
    const int bid  = blockIdx.x;
    const int tid  = threadIdx.x;
    const int lane = tid & 63;
    const int wid  = tid >> 6;

    if (bid >= 512) {
        // -------- head(step-1): 128 blocks x 32 rows (4 waves x 8 rows) --------
        if (step > 0) {
            const int base = (bid - 512) * 32 + wid * 8;
#pragma unroll
            for (int rr = 0; rr < 8; ++rr)
                head_row(h1h_p, base + rr, Wamp, bamp, Wph, bph, bits,
                         amp, phase, nup, ndn, out, step - 1, lane);
        }
        return;
    }

    // -------- step1 GEMM + fused gates0 (R16-identical) --------
    const int j0 = (bid & 7) * 64;
    const int m0 = (bid >> 3) * 64;

    __shared__ __align__(16) _Float16 As[64 * BK];    // 8 KB
    __shared__ __align__(16) _Float16 Bs[192 * BK];   // 24 KB

    const int wm = wid >> 1, wj = wid & 1;
    const int ku = lane >> 4;

    floatx4 acc[2][2][3];
    const floatx4 z4 = {0.f, 0.f, 0.f, 0.f};
#pragma unroll
    for (int a = 0; a < 2; ++a)
#pragma unroll
        for (int b = 0; b < 2; ++b)
#pragma unroll
            for (int g = 0; g < 3; ++g) acc[a][b][g] = z4;

    const _Float16* a_srcp[2];
#pragma unroll
    for (int k2 = 0; k2 < 2; ++k2) {
        const int p = tid + k2 * 256, row = p >> 3, c = (p & 7) ^ (row & 7);
        a_srcp[k2] = h0h_c + (size_t)(m0 + row) * KD + c * 8;
    }
    const _Float16* b_srcp[6];
#pragma unroll
    for (int k2 = 0; k2 < 6; ++k2) {
        const int p = tid + k2 * 256, row = p >> 3, c = (p & 7) ^ (row & 7);
        const int grow = (row >> 6) * HID + j0 + (row & 63);
        b_srcp[k2] = wh0 + (size_t)grow * KD + c * 8;
    }
    _Float16* a_dst[2];
#pragma unroll
    for (int k2 = 0; k2 < 2; ++k2) a_dst[k2] = As + (size_t)(k2 * 256 + wid * 64) * 8;
    _Float16* b_dst[6];
#pragma unroll
    for (int k2 = 0; k2 < 6; ++k2) b_dst[k2] = Bs + (size_t)(k2 * 256 + wid * 64) * 8;

    int aoff[2][2], boff[2][3][2];
#pragma unroll
    for (int mf = 0; mf < 2; ++mf) {
        const int r = wm * 32 + mf * 16 + (lane & 15);
#pragma unroll
        for (int kk = 0; kk < 2; ++kk)
            aoff[mf][kk] = r * BK + (((kk * 4 + ku) ^ (r & 7)) * 8);
    }
#pragma unroll
    for (int jf = 0; jf < 2; ++jf)
#pragma unroll
        for (int g = 0; g < 3; ++g) {
            const int r = g * 64 + wj * 32 + jf * 16 + (lane & 15);
#pragma unroll
            for (int kk = 0; kk < 2; ++kk)
                boff[jf][g][kk] = r * BK + (((kk * 4 + ku) ^ (r & 7)) * 8);
        }

    for (int kt = 0; kt < 8; ++kt) {
        const int k0 = kt * BK;
#pragma unroll
        for (int k2 = 0; k2 < 2; ++k2) gload16(a_srcp[k2] + k0, a_dst[k2]);
#pragma unroll
        for (int k2 = 0; k2 < 6; ++k2) gload16(b_srcp[k2] + k0, b_dst[k2]);
        __syncthreads();
#pragma unroll
        for (int kk = 0; kk < 2; ++kk) {
            half8 af[2], bf[2][3];
#pragma unroll
            for (int mf = 0; mf < 2; ++mf) af[mf] = *(const half8*)(As + aoff[mf][kk]);
#pragma unroll
            for (int jf = 0; jf < 2; ++jf)
#pragma unroll
                for (int g = 0; g < 3; ++g) bf[jf][g] = *(const half8*)(Bs + boff[jf][g][kk]);
#pragma unroll
            for (int mf = 0; mf < 2; ++mf)
#pragma unroll
                for (int jf = 0; jf < 2; ++jf)
#pragma unroll
                    for (int g = 0; g < 3; ++g)
                        acc[mf][jf][g] = __builtin_amdgcn_mfma_f32_16x16x32_f16(
                            af[mf], bf[jf][g], acc[mf][jf][g], 0, 0, 0);
        }
        __syncthreads();
    }

    // fused gates0: h0n = (1-z)*n + z*h0
#pragma unroll
    for (int mf = 0; mf < 2; ++mf)
#pragma unroll
        for (int jf = 0; jf < 2; ++jf) {
            const floatx4 gr = acc[mf][jf][0];
            const floatx4 gz = acc[mf][jf][1];
            const floatx4 gn = acc[mf][jf][2];
#pragma unroll
            for (int reg = 0; reg < 4; ++reg) {
                const int m = m0 + wm * 32 + mf * 16 + (lane >> 4) * 4 + reg;
                const int j = j0 + wj * 32 + jf * 16 + (lane & 15);
                float gir = 0.f, giz = 0.f, gin = 0.f;
                if (step > 0) {
                    const int tb = bits[m * SORB + step - 1];
                    gir = Wih0[j * 2 + tb];
                    giz = Wih0[(HID + j) * 2 + tb];
                    gin = Wih0[(2 * HID + j) * 2 + tb];
                }
                const float r  = sigmoidf_(gir + gr[reg]);
                const float zz = sigmoidf_(giz + gz[reg]);
                const float n  = tanhf_(gin + r * gn[reg]);
                const size_t idx = (size_t)m * HID + j;
                const float h  = (float)h0h_c[idx];
                h0h_n[idx] = (_Float16)((1.f - zz) * n + zz * h);
            }
        }
}

// ================= step2: dual-K GEMM (gi1 + gh1) + fused gates1 (R16-identical) ======
__global__ __launch_bounds__(256) void step2_kernel(
    const _Float16* __restrict__ h0h_n, const _Float16* __restrict__ h1h_c,
    const _Float16* __restrict__ wi1,   const _Float16* __restrict__ wh1,
    _Float16* __restrict__ h1h_n)
{
    const int j0 = blockIdx.x * 64;
    const int m0 = blockIdx.y * 64;

    __shared__ __align__(16) _Float16 As[64 * BK];
    __shared__ __align__(16) _Float16 Bs[192 * BK];

    const int tid  = threadIdx.x;
    const int lane = tid & 63;
    const int wid  = tid >> 6;
    const int wm   = wid >> 1, wj = wid & 1;
    const int ku   = lane >> 4;

    floatx4 acc[2][2][3];
    floatx4 accn[2][2];
    const floatx4 z4 = {0.f, 0.f, 0.f, 0.f};
#pragma unroll
    for (int a = 0; a < 2; ++a)
#pragma unroll
        for (int b = 0; b < 2; ++b) {
#pragma unroll
            for (int g = 0; g < 3; ++g) acc[a][b][g] = z4;
            accn[a][b] = z4;
        }

    _Float16* a_dst[2];
#pragma unroll
    for (int k2 = 0; k2 < 2; ++k2) a_dst[k2] = As + (size_t)(k2 * 256 + wid * 64) * 8;
    _Float16* b_dst[6];
#pragma unroll
    for (int k2 = 0; k2 < 6; ++k2) b_dst[k2] = Bs + (size_t)(k2 * 256 + wid * 64) * 8;

    int aoff[2][2], boff[2][3][2];
#pragma unroll
    for (int mf = 0; mf < 2; ++mf) {
        const int r = wm * 32 + mf * 16 + (lane & 15);
#pragma unroll
        for (int kk = 0; kk < 2; ++kk)
            aoff[mf][kk] = r * BK + (((kk * 4 + ku) ^ (r & 7)) * 8);
    }
#pragma unroll
    for (int jf = 0; jf < 2; ++jf)
#pragma unroll
        for (int g = 0; g < 3; ++g) {
            const int r = g * 64 + wj * 32 + jf * 16 + (lane & 15);
#pragma unroll
            for (int kk = 0; kk < 2; ++kk)
                boff[jf][g][kk] = r * BK + (((kk * 4 + ku) ^ (r & 7)) * 8);
        }

#pragma unroll 1
    for (int half = 0; half < 2; ++half) {
        const _Float16* Aop = half ? h1h_c : h0h_n;
        const _Float16* Wop = half ? wh1  : wi1;
        const _Float16* a_srcp[2];
#pragma unroll
        for (int k2 = 0; k2 < 2; ++k2) {
            const int p = tid + k2 * 256, row = p >> 3, c = (p & 7) ^ (row & 7);
            a_srcp[k2] = Aop + (size_t)(m0 + row) * KD + c * 8;
        }
        const _Float16* b_srcp[6];
#pragma unroll
        for (int k2 = 0; k2 < 6; ++k2) {
            const int p = tid + k2 * 256, row = p >> 3, c = (p & 7) ^ (row & 7);
            const int grow = (row >> 6) * HID + j0 + (row & 63);
            b_srcp[k2] = Wop + (size_t)grow * KD + c * 8;
        }

        for (int kt = 0; kt < 8; ++kt) {
            const int k0 = kt * BK;
#pragma unroll
            for (int k2 = 0; k2 < 2; ++k2) gload16(a_srcp[k2] + k0, a_dst[k2]);
#pragma unroll
            for (int k2 = 0; k2 < 6; ++k2) gload16(b_srcp[k2] + k0, b_dst[k2]);
            __syncthreads();
#pragma unroll
            for (int kk = 0; kk < 2; ++kk) {
                half8 af[2], bf[2][3];
#pragma unroll
                for (int mf = 0; mf < 2; ++mf) af[mf] = *(const half8*)(As + aoff[mf][kk]);
#pragma unroll
                for (int jf = 0; jf < 2; ++jf)
#pragma unroll
                    for (int g = 0; g < 3; ++g) bf[jf][g] = *(const half8*)(Bs + boff[jf][g][kk]);
#pragma unroll
                for (int mf = 0; mf < 2; ++mf)
#pragma unroll
                    for (int jf = 0; jf < 2; ++jf) {
                        acc[mf][jf][0] = __builtin_amdgcn_mfma_f32_16x16x32_f16(
                            af[mf], bf[jf][0], acc[mf][jf][0], 0, 0, 0);
                        acc[mf][jf][1] = __builtin_amdgcn_mfma_f32_16x16x32_f16(
                            af[mf], bf[jf][1], acc[mf][jf][1], 0, 0, 0);
                        if (half == 0)
                            acc[mf][jf][2] = __builtin_amdgcn_mfma_f32_16x16x32_f16(
                                af[mf], bf[jf][2], acc[mf][jf][2], 0, 0, 0);
                        else
                            accn[mf][jf] = __builtin_amdgcn_mfma_f32_16x16x32_f16(
                                af[mf], bf[jf][2], accn[mf][jf], 0, 0, 0);
                    }
            }
            __syncthreads();
        }
    }

    // fused gates1: r=sig(gi_r+gh_r), z=sig(gi_z+gh_z), n=tanh(gi_n + r*gh_n)
#pragma unroll
    for (int mf = 0; mf < 2; ++mf)
#pragma unroll
        for (int jf = 0; jf < 2; ++jf) {
            const floatx4 grz = acc[mf][jf][0];
            const floatx4 gzz = acc[mf][jf][1];
            const floatx4 gin = acc[mf][jf][2];
            const floatx4 ghn = accn[mf][jf];
#pragma unroll
            for (int reg = 0; reg < 4; ++reg) {
                const int m = m0 + wm * 32 + mf * 16 + (lane >> 4) * 4 + reg;
                const int j = j0 + wj * 32 + jf * 16 + (lane & 15);
                const float r  = sigmoidf_(grz[reg]);
                const float zz = sigmoidf_(gzz[reg]);
                const float n  = tanhf_(gin[reg] + r * ghn[reg]);
                const size_t idx = (size_t)m * HID + j;
                const float h  = (float)h1h_c[idx];
                h1h_n[idx] = (_Float16)((1.f - zz) * n + zz * h);
            }
        }
}

// ================= final head (step 63) =================
__global__ __launch_bounds__(256) void head_kernel(
    const _Float16* __restrict__ h1h_n,
    const float* __restrict__ Wamp, const float* __restrict__ bamp,
    const float* __restrict__ Wph,  const float* __restrict__ bph,
    const int* __restrict__ bits,
    float* __restrict__ amp, float* __restrict__ phase,
    int* __restrict__ nup, int* __restrict__ ndn,
    float* __restrict__ out, int step)
{
    const int lane = threadIdx.x & 63;
    const int m    = blockIdx.x * 4 + (threadIdx.x >> 6);
    head_row(h1h_n, m, Wamp, bamp, Wph, bph, bits, amp, phase, nup, ndn, out, step, lane);
}

extern "C" void kernel_launch(void* const* d_in, const int* in_sizes, int n_in,
                              void* d_out, int out_size, void* d_ws, size_t ws_size,
                              hipStream_t stream) {
    const int*   bits = (const int*)d_in[0];
    const float* Wih0 = (const float*)d_in[1];
    const float* Whh0 = (const float*)d_in[2];
    const float* Wih1 = (const float*)d_in[3];
    const float* Whh1 = (const float*)d_in[4];
    const float* Wamp = (const float*)d_in[5];
    const float* bamp = (const float*)d_in[6];
    const float* Wph  = (const float*)d_in[7];
    const float* bph  = (const float*)d_in[8];
    float* out = (float*)d_out;

    char* ws = (char*)d_ws;
    size_t off = 0;
    auto alloc = [&](size_t bytes) {
        void* p = ws + off;
        off = (off + bytes + 255) & ~(size_t)255;
        return p;
    };
    _Float16* wh0 = (_Float16*)alloc((size_t)N3H * KD * 2);
    _Float16* wi1 = (_Float16*)alloc((size_t)N3H * KD * 2);
    _Float16* wh1 = (_Float16*)alloc((size_t)N3H * KD * 2);
    _Float16* h0hA = (_Float16*)alloc((size_t)BATCH * HID * 2);
    _Float16* h0hB = (_Float16*)alloc((size_t)BATCH * HID * 2);
    _Float16* h1hA = (_Float16*)alloc((size_t)BATCH * HID * 2);
    _Float16* h1hB = (_Float16*)alloc((size_t)BATCH * HID * 2);
    float*    amp   = (float*)alloc((size_t)BATCH * 4);
    float*    phase = (float*)alloc((size_t)BATCH * 4);
    int*      nup   = (int*)alloc((size_t)BATCH * 4);
    int*      ndn   = (int*)alloc((size_t)BATCH * 4);

    _Float16* h0h[2] = {h0hA, h0hB};
    _Float16* h1h[2] = {h1hA, h1hB};

    hipMemsetAsync(h0hA, 0, (size_t)BATCH * HID * 2, stream);
    hipMemsetAsync(h1hA, 0, (size_t)BATCH * HID * 2, stream);
    convw_kernel<<<(N3H * KD + 255) / 256, 256, 0, stream>>>(Whh0, Wih1, Whh1, wh0, wi1, wh1);
    init_kernel<<<BATCH / 256, 256, 0, stream>>>(amp, phase, nup, ndn);

    for (int s = 0; s < SORB; ++s) {
        const int cur = s & 1, nxt = cur ^ 1;
        // dispatch: step1(s) [512 blocks] || head(s-1) [128 blocks]
        step1_kernel<<<640, 256, 0, stream>>>(
            h0h[cur], wh0, Wih0, bits, h0h[nxt], s,
            h1h[cur],                       // h1h written by step2(s-1) = h1h[cur(s)]
            Wamp, bamp, Wph, bph, amp, phase, nup, ndn, out);
        step2_kernel<<<dim3(8, 64), 256, 0, stream>>>(
            h0h[nxt], h1h[cur], wi1, wh1, h1h[nxt]);
    }
    head_kernel<<<BATCH / 4, 256, 0, stream>>>(
        h1h[0], Wamp, bamp, Wph, bph, bits, amp, phase, nup, ndn, out, SORB - 1);
}

// Round 23
// 2764.113 us; speedup vs baseline: 1.3346x; 1.0226x over previous
//
#include <hip/hip_runtime.h>
#include <hip/hip_bf16.h>

#define SORB  64
#define HID   512
#define BATCH 4096
#define N3H   1536
#define KD    512
#define BK    64
#define PI_F  3.14159265358979f

typedef _Float16 half8 __attribute__((ext_vector_type(8)));
typedef float    floatx4 __attribute__((ext_vector_type(4)));

__device__ __forceinline__ void gload16(const void* g, void* l) {
    __builtin_amdgcn_global_load_lds(
        (const __attribute__((address_space(1))) void*)g,
        (__attribute__((address_space(3))) void*)l, 16, 0, 0);
}

__device__ __forceinline__ float sigmoidf_(float x) { return 1.f / (1.f + __expf(-x)); }
__device__ __forceinline__ float tanhf_(float x) {
    x = fminf(fmaxf(x, -15.f), 15.f);
    const float e2 = __expf(2.f * x);
    return (e2 - 1.f) / (e2 + 1.f);
}

__global__ __launch_bounds__(256) void convw_kernel(
    const float* __restrict__ w0, const float* __restrict__ w1, const float* __restrict__ w2,
    _Float16* __restrict__ o0, _Float16* __restrict__ o1, _Float16* __restrict__ o2)
{
    const int i = blockIdx.x * 256 + threadIdx.x;
    if (i < N3H * KD) {
        o0[i] = (_Float16)w0[i];
        o1[i] = (_Float16)w1[i];
        o2[i] = (_Float16)w2[i];
    }
}

__global__ __launch_bounds__(256) void init_kernel(
    float* __restrict__ amp, float* __restrict__ phase,
    int* __restrict__ nup, int* __restrict__ ndn)
{
    const int i = blockIdx.x * 256 + threadIdx.x;
    if (i < BATCH) { amp[i] = 1.f; phase[i] = 0.f; nup[i] = 0; ndn[i] = 0; }
}

// ---------------- head row (R16-verified) ----------------
__device__ __forceinline__ void head_row(
    const _Float16* __restrict__ h1, int m,
    const float* __restrict__ Wamp, const float* __restrict__ bamp,
    const float* __restrict__ Wph,  const float* __restrict__ bph,
    const int* __restrict__ bits,
    float* __restrict__ amp, float* __restrict__ phase,
    int* __restrict__ nup, int* __restrict__ ndn,
    float* __restrict__ out, int step, int lane)
{
    const half8 hv = *(const half8*)(h1 + (size_t)m * HID + lane * 8);
    float d0 = 0.f, d1 = 0.f, d2 = 0.f, d3 = 0.f;
#pragma unroll
    for (int e = 0; e < 8; ++e) {
        const int j = lane * 8 + e;
        const float hn = (float)hv[e];
        d0 += hn * Wamp[j];       d1 += hn * Wamp[HID + j];
        d2 += hn * Wph[j];        d3 += hn * Wph[HID + j];
    }
#pragma unroll
    for (int off = 1; off < 64; off <<= 1) {
        d0 += __shfl_xor(d0, off); d1 += __shfl_xor(d1, off);
        d2 += __shfl_xor(d2, off); d3 += __shfl_xor(d3, off);
    }
    if (lane == 0) {
        const float a0 = d0 + bamp[0];
        const float a1 = d1 + bamp[1];
        const float mx = fmaxf(a0, a1);
        const float e0 = __expf(a0 - mx), e1 = __expf(a1 - mx);
        const float inv = 1.f / (e0 + e1);
        float ya0 = sqrtf(e0 * inv), ya1 = sqrtf(e1 * inv);
        const float p0 = d2 + bph[0];
        const float p1 = d3 + bph[1];
        const float yp0 = PI_F * p0 / (1.f + fabsf(p0));
        const float yp1 = PI_F * p1 / (1.f + fabsf(p1));
        const int even = ((step & 1) == 0);
        const int cnt = even ? nup[m] : ndn[m];
        if (step >= 32) {  // MIN_I
            const int lower = (step >> 1) - 16;
            const float m0v = (cnt > lower) ? ya0 : 0.f;
            const float m1v = (cnt < 16) ? ya1 : 0.f;
            const float nrm = sqrtf(m0v * m0v + m1v * m1v + 1e-12f);
            ya0 = m0v / nrm; ya1 = m1v / nrm;
        }
        const int bi = bits[m * SORB + step];
        const float na = amp[m] * (bi ? ya1 : ya0);
        const float np = phase[m] + (bi ? yp1 : yp0);
        amp[m] = na; phase[m] = np;
        if (bi) { if (even) nup[m] = cnt + 1; else ndn[m] = cnt + 1; }
        if (step == SORB - 1) {
            out[m * 2 + 0] = na;
            out[m * 2 + 1] = np;
        }
    }
}

// ====== launch A: gh0+gates0 [0..511] || gh1->gB [512..1023] || head(s-1) [1024..1151]
// All three read only (s-1)-state: gh0 reads h0h_c, gh1+head read h1h_c.
// Writes disjoint: h0h_n / gB / per-row scalars.  1024 GEMM blocks = 4/CU.
__global__ __launch_bounds__(256) void step1_kernel(
    const _Float16* __restrict__ h0h_c, const _Float16* __restrict__ h1h_c,
    const _Float16* __restrict__ wh0,   const _Float16* __restrict__ wh1,
    const float* __restrict__ Wih0, const int* __restrict__ bits,
    _Float16* __restrict__ h0h_n, _Float16* __restrict__ gB, int step,
    const float* __restrict__ Wamp, const float* __restrict__ bamp,
    const float* __restrict__ Wph,  const float* __restrict__ bph,
    float* __restrict__ amp, float* __restrict__ phase,
    int* __restrict__ nup, int* __restrict__ ndn, float* __restrict__ out)
{
    const int bid  = blockIdx.x;
    const int tid  = threadIdx.x;
    const int lane = tid & 63;
    const int wid  = tid >> 6;

    if (bid >= 1024) {
        // -------- head(step-1): 128 blocks x 32 rows --------
        if (step > 0) {
            const int base = (bid - 1024) * 32 + wid * 8;
#pragma unroll
            for (int rr = 0; rr < 8; ++rr)
                head_row(h1h_c, base + rr, Wamp, bamp, Wph, bph, bits,
                         amp, phase, nup, ndn, out, step - 1, lane);
        }
        return;
    }

    const int z  = bid >> 9;                 // 0: gh0, 1: gh1
    const int t  = bid & 511;
    const int j0 = (t & 7) * 64;
    const int m0 = (t >> 3) * 64;
    const _Float16* Aop = z ? h1h_c : h0h_c;
    const _Float16* Wop = z ? wh1 : wh0;

    __shared__ __align__(16) _Float16 As[64 * BK];    // 8 KB
    __shared__ __align__(16) _Float16 Bs[192 * BK];   // 24 KB

    const int wm = wid >> 1, wj = wid & 1;
    const int ku = lane >> 4;

    floatx4 acc[2][2][3];
    const floatx4 z4 = {0.f, 0.f, 0.f, 0.f};
#pragma unroll
    for (int a = 0; a < 2; ++a)
#pragma unroll
        for (int b = 0; b < 2; ++b)
#pragma unroll
            for (int g = 0; g < 3; ++g) acc[a][b][g] = z4;

    const _Float16* a_srcp[2];
#pragma unroll
    for (int k2 = 0; k2 < 2; ++k2) {
        const int p = tid + k2 * 256, row = p >> 3, c = (p & 7) ^ (row & 7);
        a_srcp[k2] = Aop + (size_t)(m0 + row) * KD + c * 8;
    }
    const _Float16* b_srcp[6];
#pragma unroll
    for (int k2 = 0; k2 < 6; ++k2) {
        const int p = tid + k2 * 256, row = p >> 3, c = (p & 7) ^ (row & 7);
        const int grow = (row >> 6) * HID + j0 + (row & 63);
        b_srcp[k2] = Wop + (size_t)grow * KD + c * 8;
    }
    _Float16* a_dst[2];
#pragma unroll
    for (int k2 = 0; k2 < 2; ++k2) a_dst[k2] = As + (size_t)(k2 * 256 + wid * 64) * 8;
    _Float16* b_dst[6];
#pragma unroll
    for (int k2 = 0; k2 < 6; ++k2) b_dst[k2] = Bs + (size_t)(k2 * 256 + wid * 64) * 8;

    int aoff[2][2], boff[2][3][2];
#pragma unroll
    for (int mf = 0; mf < 2; ++mf) {
        const int r = wm * 32 + mf * 16 + (lane & 15);
#pragma unroll
        for (int kk = 0; kk < 2; ++kk)
            aoff[mf][kk] = r * BK + (((kk * 4 + ku) ^ (r & 7)) * 8);
    }
#pragma unroll
    for (int jf = 0; jf < 2; ++jf)
#pragma unroll
        for (int g = 0; g < 3; ++g) {
            const int r = g * 64 + wj * 32 + jf * 16 + (lane & 15);
#pragma unroll
            for (int kk = 0; kk < 2; ++kk)
                boff[jf][g][kk] = r * BK + (((kk * 4 + ku) ^ (r & 7)) * 8);
        }

    for (int kt = 0; kt < 8; ++kt) {
        const int k0 = kt * BK;
#pragma unroll
        for (int k2 = 0; k2 < 2; ++k2) gload16(a_srcp[k2] + k0, a_dst[k2]);
#pragma unroll
        for (int k2 = 0; k2 < 6; ++k2) gload16(b_srcp[k2] + k0, b_dst[k2]);
        __syncthreads();
#pragma unroll
        for (int kk = 0; kk < 2; ++kk) {
            half8 af[2], bf[2][3];
#pragma unroll
            for (int mf = 0; mf < 2; ++mf) af[mf] = *(const half8*)(As + aoff[mf][kk]);
#pragma unroll
            for (int jf = 0; jf < 2; ++jf)
#pragma unroll
                for (int g = 0; g < 3; ++g) bf[jf][g] = *(const half8*)(Bs + boff[jf][g][kk]);
#pragma unroll
            for (int mf = 0; mf < 2; ++mf)
#pragma unroll
                for (int jf = 0; jf < 2; ++jf)
#pragma unroll
                    for (int g = 0; g < 3; ++g)
                        acc[mf][jf][g] = __builtin_amdgcn_mfma_f32_16x16x32_f16(
                            af[mf], bf[jf][g], acc[mf][jf][g], 0, 0, 0);
        }
        __syncthreads();
    }

    if (z == 0) {
        // fused gates0: h0n = (1-z)*n + z*h0
#pragma unroll
        for (int mf = 0; mf < 2; ++mf)
#pragma unroll
            for (int jf = 0; jf < 2; ++jf) {
                const floatx4 gr = acc[mf][jf][0];
                const floatx4 gz = acc[mf][jf][1];
                const floatx4 gn = acc[mf][jf][2];
#pragma unroll
                for (int reg = 0; reg < 4; ++reg) {
                    const int m = m0 + wm * 32 + mf * 16 + (lane >> 4) * 4 + reg;
                    const int j = j0 + wj * 32 + jf * 16 + (lane & 15);
                    float gir = 0.f, giz = 0.f, gin = 0.f;
                    if (step > 0) {
                        const int tb = bits[m * SORB + step - 1];
                        gir = Wih0[j * 2 + tb];
                        giz = Wih0[(HID + j) * 2 + tb];
                        gin = Wih0[(2 * HID + j) * 2 + tb];
                    }
                    const float r  = sigmoidf_(gir + gr[reg]);
                    const float zz = sigmoidf_(giz + gz[reg]);
                    const float n  = tanhf_(gin + r * gn[reg]);
                    const size_t idx = (size_t)m * HID + j;
                    const float h  = (float)h0h_c[idx];
                    h0h_n[idx] = (_Float16)((1.f - zz) * n + zz * h);
                }
            }
    } else {
        // store gh1 to gB in [r|z|n] layout
#pragma unroll
        for (int mf = 0; mf < 2; ++mf)
#pragma unroll
            for (int jf = 0; jf < 2; ++jf)
#pragma unroll
                for (int g = 0; g < 3; ++g)
#pragma unroll
                    for (int reg = 0; reg < 4; ++reg) {
                        const int m = m0 + wm * 32 + mf * 16 + (lane >> 4) * 4 + reg;
                        const int j = j0 + wj * 32 + jf * 16 + (lane & 15);
                        gB[(size_t)m * N3H + g * HID + j] = (_Float16)acc[mf][jf][g][reg];
                    }
    }
}

// ====== launch B: gi1 GEMM (K=512) + gB read + fused gates1 (R11-verified form) ======
__global__ __launch_bounds__(256) void step2_kernel(
    const _Float16* __restrict__ h0h_n, const _Float16* __restrict__ h1h_c,
    const _Float16* __restrict__ wi1,   const _Float16* __restrict__ gB,
    _Float16* __restrict__ h1h_n)
{
    const int j0 = blockIdx.x * 64;
    const int m0 = blockIdx.y * 64;

    __shared__ __align__(16) _Float16 As[64 * BK];
    __shared__ __align__(16) _Float16 Bs[192 * BK];

    const int tid  = threadIdx.x;
    const int lane = tid & 63;
    const int wid  = tid >> 6;
    const int wm   = wid >> 1, wj = wid & 1;
    const int ku   = lane >> 4;

    floatx4 acc[2][2][3];
    const floatx4 z4 = {0.f, 0.f, 0.f, 0.f};
#pragma unroll
    for (int a = 0; a < 2; ++a)
#pragma unroll
        for (int b = 0; b < 2; ++b)
#pragma unroll
            for (int g = 0; g < 3; ++g) acc[a][b][g] = z4;

    const _Float16* a_srcp[2];
#pragma unroll
    for (int k2 = 0; k2 < 2; ++k2) {
        const int p = tid + k2 * 256, row = p >> 3, c = (p & 7) ^ (row & 7);
        a_srcp[k2] = h0h_n + (size_t)(m0 + row) * KD + c * 8;
    }
    const _Float16* b_srcp[6];
#pragma unroll
    for (int k2 = 0; k2 < 6; ++k2) {
        const int p = tid + k2 * 256, row = p >> 3, c = (p & 7) ^ (row & 7);
        const int grow = (row >> 6) * HID + j0 + (row & 63);
        b_srcp[k2] = wi1 + (size_t)grow * KD + c * 8;
    }
    _Float16* a_dst[2];
#pragma unroll
    for (int k2 = 0; k2 < 2; ++k2) a_dst[k2] = As + (size_t)(k2 * 256 + wid * 64) * 8;
    _Float16* b_dst[6];
#pragma unroll
    for (int k2 = 0; k2 < 6; ++k2) b_dst[k2] = Bs + (size_t)(k2 * 256 + wid * 64) * 8;

    int aoff[2][2], boff[2][3][2];
#pragma unroll
    for (int mf = 0; mf < 2; ++mf) {
        const int r = wm * 32 + mf * 16 + (lane & 15);
#pragma unroll
        for (int kk = 0; kk < 2; ++kk)
            aoff[mf][kk] = r * BK + (((kk * 4 + ku) ^ (r & 7)) * 8);
    }
#pragma unroll
    for (int jf = 0; jf < 2; ++jf)
#pragma unroll
        for (int g = 0; g < 3; ++g) {
            const int r = g * 64 + wj * 32 + jf * 16 + (lane & 15);
#pragma unroll
            for (int kk = 0; kk < 2; ++kk)
                boff[jf][g][kk] = r * BK + (((kk * 4 + ku) ^ (r & 7)) * 8);
        }

    for (int kt = 0; kt < 8; ++kt) {
        const int k0 = kt * BK;
#pragma unroll
        for (int k2 = 0; k2 < 2; ++k2) gload16(a_srcp[k2] + k0, a_dst[k2]);
#pragma unroll
        for (int k2 = 0; k2 < 6; ++k2) gload16(b_srcp[k2] + k0, b_dst[k2]);
        __syncthreads();
#pragma unroll
        for (int kk = 0; kk < 2; ++kk) {
            half8 af[2], bf[2][3];
#pragma unroll
            for (int mf = 0; mf < 2; ++mf) af[mf] = *(const half8*)(As + aoff[mf][kk]);
#pragma unroll
            for (int jf = 0; jf < 2; ++jf)
#pragma unroll
                for (int g = 0; g < 3; ++g) bf[jf][g] = *(const half8*)(Bs + boff[jf][g][kk]);
#pragma unroll
            for (int mf = 0; mf < 2; ++mf)
#pragma unroll
                for (int jf = 0; jf < 2; ++jf)
#pragma unroll
                    for (int g = 0; g < 3; ++g)
                        acc[mf][jf][g] = __builtin_amdgcn_mfma_f32_16x16x32_f16(
                            af[mf], bf[jf][g], acc[mf][jf][g], 0, 0, 0);
        }
        __syncthreads();
    }

    // fused gates1: r=sig(gi_r+gh_r), z=sig(gi_z+gh_z), n=tanh(gi_n + r*gh_n)
#pragma unroll
    for (int mf = 0; mf < 2; ++mf)
#pragma unroll
        for (int jf = 0; jf < 2; ++jf) {
            const floatx4 gr = acc[mf][jf][0];
            const floatx4 gz = acc[mf][jf][1];
            const floatx4 gn = acc[mf][jf][2];
#pragma unroll
            for (int reg = 0; reg < 4; ++reg) {
                const int m = m0 + wm * 32 + mf * 16 + (lane >> 4) * 4 + reg;
                const int j = j0 + wj * 32 + jf * 16 + (lane & 15);
                const size_t gbase = (size_t)m * N3H;
                const float ghr = (float)gB[gbase + j];
                const float ghz = (float)gB[gbase + HID + j];
                const float ghn = (float)gB[gbase + 2 * HID + j];
                const float r  = sigmoidf_(gr[reg] + ghr);
                const float zz = sigmoidf_(gz[reg] + ghz);
                const float n  = tanhf_(gn[reg] + r * ghn);
                const size_t idx = (size_t)m * HID + j;
                const float h  = (float)h1h_c[idx];
                h1h_n[idx] = (_Float16)((1.f - zz) * n + zz * h);
            }
        }
}

// ================= final head (step 63) =================
__global__ __launch_bounds__(256) void head_kernel(
    const _Float16* __restrict__ h1h_n,
    const float* __restrict__ Wamp, const float* __restrict__ bamp,
    const float* __restrict__ Wph,  const float* __restrict__ bph,
    const int* __restrict__ bits,
    float* __restrict__ amp, float* __restrict__ phase,
    int* __restrict__ nup, int* __restrict__ ndn,
    float* __restrict__ out, int step)
{
    const int lane = threadIdx.x & 63;
    const int m    = blockIdx.x * 4 + (threadIdx.x >> 6);
    head_row(h1h_n, m, Wamp, bamp, Wph, bph, bits, amp, phase, nup, ndn, out, step, lane);
}

extern "C" void kernel_launch(void* const* d_in, const int* in_sizes, int n_in,
                              void* d_out, int out_size, void* d_ws, size_t ws_size,
                              hipStream_t stream) {
    const int*   bits = (const int*)d_in[0];
    const float* Wih0 = (const float*)d_in[1];
    const float* Whh0 = (const float*)d_in[2];
    const float* Wih1 = (const float*)d_in[3];
    const float* Whh1 = (const float*)d_in[4];
    const float* Wamp = (const float*)d_in[5];
    const float* bamp = (const float*)d_in[6];
    const float* Wph  = (const float*)d_in[7];
    const float* bph  = (const float*)d_in[8];
    float* out = (float*)d_out;

    char* ws = (char*)d_ws;
    size_t off = 0;
    auto alloc = [&](size_t bytes) {
        void* p = ws + off;
        off = (off + bytes + 255) & ~(size_t)255;
        return p;
    };
    _Float16* wh0 = (_Float16*)alloc((size_t)N3H * KD * 2);
    _Float16* wi1 = (_Float16*)alloc((size_t)N3H * KD * 2);
    _Float16* wh1 = (_Float16*)alloc((size_t)N3H * KD * 2);
    _Float16* h0hA = (_Float16*)alloc((size_t)BATCH * HID * 2);
    _Float16* h0hB = (_Float16*)alloc((size_t)BATCH * HID * 2);
    _Float16* h1hA = (_Float16*)alloc((size_t)BATCH * HID * 2);
    _Float16* h1hB = (_Float16*)alloc((size_t)BATCH * HID * 2);
    _Float16* gB   = (_Float16*)alloc((size_t)BATCH * N3H * 2);
    float*    amp   = (float*)alloc((size_t)BATCH * 4);
    float*    phase = (float*)alloc((size_t)BATCH * 4);
    int*      nup   = (int*)alloc((size_t)BATCH * 4);
    int*      ndn   = (int*)alloc((size_t)BATCH * 4);

    _Float16* h0h[2] = {h0hA, h0hB};
    _Float16* h1h[2] = {h1hA, h1hB};

    hipMemsetAsync(h0hA, 0, (size_t)BATCH * HID * 2, stream);
    hipMemsetAsync(h1hA, 0, (size_t)BATCH * HID * 2, stream);
    convw_kernel<<<(N3H * KD + 255) / 256, 256, 0, stream>>>(Whh0, Wih1, Whh1, wh0, wi1, wh1);
    init_kernel<<<BATCH / 256, 256, 0, stream>>>(amp, phase, nup, ndn);

    for (int s = 0; s < SORB; ++s) {
        const int cur = s & 1, nxt = cur ^ 1;
        // launch A: gh0+gates0 || gh1->gB || head(s-1)
        step1_kernel<<<1152, 256, 0, stream>>>(
            h0h[cur], h1h[cur], wh0, wh1, Wih0, bits, h0h[nxt], gB, s,
            Wamp, bamp, Wph, bph, amp, phase, nup, ndn, out);
        // launch B: gi1 + gB + gates1
        step2_kernel<<<dim3(8, 64), 256, 0, stream>>>(
            h0h[nxt], h1h[cur], wi1, gB, h1h[nxt]);
    }
    head_kernel<<<BATCH / 4, 256, 0, stream>>>(
        h1h[0], Wamp, bamp, Wph, bph, bits, amp, phase, nup, ndn, out, SORB - 1);
}